// Round 5
// baseline (749.050 us; speedup 1.0000x reference)
//
#include <hip/hip_runtime.h>
#include <stdint.h>

#define NODES   8192
#define BATCH   8
#define FIN     16
#define HC1     64
#define HC2     1024
#define DTOT    1048576
#define NEG     0.2f

typedef unsigned short u16;

__device__ __forceinline__ float b2f(u16 s){ return __uint_as_float(((unsigned)s)<<16); }
__device__ __forceinline__ u16 f2b(float f){
    unsigned u = __float_as_uint(f);
    unsigned r = u + 0x7fffu + ((u>>16)&1u);
    return (u16)(r>>16);
}
__device__ __forceinline__ float lrelu(float x){ return x > 0.f ? x : NEG*x; }
__device__ __forceinline__ float ldf(const void* p, long i, int isf){
    return isf ? ((const float*)p)[i] : b2f(((const u16*)p)[i]);
}

__device__ __forceinline__ int esrc(const int* e, int i, int i64){ return i64 ? e[2*i] : e[i]; }
__device__ __forceinline__ int edst(const int* e, int i, int E, int i64){ return i64 ? e[2*(E+i)] : e[E+i]; }

// ---------- prep: dtype detect (block 0) + zero counts ----------
__global__ __launch_bounds__(256) void k_prep(const u16* __restrict__ xs, const int* __restrict__ ed,
        int* flags, int* counts){
    int t = threadIdx.x;
    if(blockIdx.x == 0){
        __shared__ int cnt[2];
        if(t<2) cnt[t]=0;
        __syncthreads();
        int bad=0;
        for(int i=t;i<1024;i+=256){
            u16 u = xs[i];
            float a = fabsf(b2f(u));
            if(!(u==0 || (a>1e-8f && a<1e4f))) bad++;
        }
        if(bad) atomicAdd(&cnt[0], bad);
        int z=0;
        for(int i=t;i<1024;i+=256){
            if(ed[2*i+1]==0) z++;
        }
        if(z) atomicAdd(&cnt[1], z);
        __syncthreads();
        if(t==0){ flags[0] = (cnt[0] > 64) ? 1 : 0; flags[1] = (cnt[1] > 512) ? 1 : 0; }
    } else {
        int i = (blockIdx.x-1)*256 + t;
        if(i < NODES) counts[i] = 0;
    }
}

// ---------- count (0..511) || as1/ad1 = x @ (W1@a1) (512..575) ----------
__global__ __launch_bounds__(256) void k_cnt_a1(const int* __restrict__ ed, int E, int* counts,
        const void* __restrict__ x, const void* __restrict__ W1,
        const void* __restrict__ asw, const void* __restrict__ adw,
        float* as1, float* ad1, const int* flags){
    int t = threadIdx.x;
    if(blockIdx.x < 512){
        int i64 = flags[1];
        int e = blockIdx.x*256 + t;
        if(e < E) atomicAdd(&counts[edst(ed,e,E,i64)], 1);
        return;
    }
    int isf = flags[0];
    __shared__ float w1l[FIN*HC1];     // 16x64
    __shared__ float p1[2][FIN][8];    // P1 = W1 @ a_{src,dst}
    __shared__ float xl[128][FIN];
    int n0 = (blockIdx.x-512)*128;
    for(int q=0;q<4;q++) w1l[t + q*256] = ldf(W1, t + q*256, isf);
    for(int q=0;q<8;q++){ int f = t + q*256; xl[f>>4][f&15] = ldf(x, (long)n0*FIN + f, isf); }
    __syncthreads();
    {   // one P1 entry per thread: sd = t>>7, k = (t>>3)&15, h = t&7
        int sd = t>>7, k = (t>>3)&15, h = t&7;
        const void* av = sd ? adw : asw;
        float s = 0.f;
        #pragma unroll
        for(int c=0;c<8;c++) s += w1l[k*HC1 + h*8 + c] * ldf(av, h*8+c, isf);
        p1[sd][k][h] = s;
    }
    __syncthreads();
    {   // node i = t>>1, sd = t&1, all 8 heads
        int i = t>>1, sd = t&1;
        float* outp = sd ? ad1 : as1;
        #pragma unroll
        for(int h=0;h<8;h++){
            float s = 0.f;
            #pragma unroll
            for(int k=0;k<FIN;k++) s += xl[i][k] * p1[sd][k][h];
            outp[(size_t)(n0+i)*8 + h] = s;
        }
    }
}

// ---------- exclusive scan ----------
__global__ __launch_bounds__(1024) void k_scan(const int* __restrict__ counts, int* offs, int* cursor){
    __shared__ int sums[1024];
    int t = threadIdx.x;
    int base = t*8;
    int loc[8]; int s = 0;
    for(int k=0;k<8;k++){ loc[k] = s; s += counts[base+k]; }
    sums[t] = s;
    __syncthreads();
    for(int off=1; off<1024; off<<=1){
        int v = (t>=off) ? sums[t-off] : 0;
        __syncthreads();
        sums[t] += v;
        __syncthreads();
    }
    int b = (t==0) ? 0 : sums[t-1];
    for(int k=0;k<8;k++){ int v = b + loc[k]; offs[base+k]=v; cursor[base+k]=v; }
    if(t==1023) offs[NODES] = sums[1023];
}

// ---------- CSR fill (0..511) || P2 = W2 @ a2 (block 512) ----------
__global__ __launch_bounds__(256) void k_fill_p2(const int* __restrict__ ed, int E, int* cursor, int* csr,
        const void* __restrict__ W2, const void* __restrict__ asw2, const void* __restrict__ adw2,
        float* p2s, float* p2d, const int* flags){
    int t = threadIdx.x;
    if(blockIdx.x < 512){
        int i64 = flags[1];
        int e = blockIdx.x*256 + t;
        if(e < E){ int p = atomicAdd(&cursor[edst(ed,e,E,i64)], 1); csr[p] = esrc(ed,e,i64); }
        return;
    }
    int isf = flags[0];
    // 1024 tasks: sd(2) x k(64) x h(8); 4 per thread
    for(int q=0;q<4;q++){
        int task = t + q*256;
        int sd = task>>9, k = (task>>3)&63, h = task&7;
        const void* av = sd ? adw2 : asw2;
        float s = 0.f;
        for(int c=0;c<128;c++) s += ldf(W2, (long)k*HC2 + h*128 + c, isf) * ldf(av, h*128+c, isf);
        (sd ? p2d : p2s)[k*8 + h] = s;
    }
}

// ---------- layer1 fused: softmax + aggregate x (per head) + @W1 + relu + as2/ad2 ----------
__global__ __launch_bounds__(64) void k_l1(const int* __restrict__ offs, const int* __restrict__ csr,
        const void* __restrict__ x, const void* __restrict__ W1, const void* __restrict__ b1,
        const float* __restrict__ as1, const float* __restrict__ ad1,
        const float* __restrict__ p2s, const float* __restrict__ p2d,
        float* z1, float* as2, float* ad2, const int* flags){
    int isf = flags[0];
    __shared__ float w1l[FIN*HC1];
    __shared__ float redm[64], redd[64];
    __shared__ float mh[8], dh[8], adl[8];
    __shared__ int src_l[64];
    __shared__ float wx[64*8];
    __shared__ float aggx[8][FIN];
    __shared__ float zl[HC1];
    int n = blockIdx.x, t = threadIdx.x;
    int off = offs[n], deg = offs[n+1]-off, tot = deg+1;
    for(int q=0;q<16;q++) w1l[t + q*64] = ldf(W1, t + q*64, isf);
    if(t<8) adl[t] = ad1[n*8+t];
    __syncthreads();
    {   // online softmax header (8-lane groups per head)
        int h = t&7, jg = t>>3;
        float ad = adl[h];
        float m = -1e30f, d = 0.f;
        for(int j=jg; j<tot; j+=8){
            int s = (j<deg)?csr[off+j]:n;
            float e = lrelu(as1[s*8+h] + ad);
            if(e>m){ d = d*__expf(m-e) + 1.f; m = e; } else d += __expf(e-m);
        }
        redm[t]=m; redd[t]=d;
        __syncthreads();
        for(int st=4; st>=1; st>>=1){
            if(jg < st){
                float m2 = redm[t + st*8], d2 = redd[t + st*8];
                float mm = fmaxf(m, m2);
                d = d*__expf(m-mm) + d2*__expf(m2-mm);
                m = mm;
                redm[t]=m; redd[t]=d;
            }
            __syncthreads();
        }
        if(t<8){ mh[t]=redm[t]; dh[t]=redd[t] + 1e-16f; }
        __syncthreads();
    }
    int c = t&15, hq = t>>4;           // lane owns x-channel c, heads hq and hq+4
    float acc0 = 0.f, acc1 = 0.f;
    for(int c0=0;c0<tot;c0+=64){
        int nc = min(64, tot-c0);
        if(t<nc){ int j=c0+t; src_l[t]=(j<deg)?csr[off+j]:n; }
        __syncthreads();
        for(int p=t;p<nc*8;p+=64){
            int j=p>>3, hh=p&7;
            float e = lrelu(as1[src_l[j]*8+hh] + adl[hh]);
            wx[p] = __expf(e - mh[hh]);
        }
        __syncthreads();
        int j = 0;
        for(; j+2<=nc; j+=2){
            float x0 = ldf(x, (long)src_l[j]*FIN + c, isf);
            float x1 = ldf(x, (long)src_l[j+1]*FIN + c, isf);
            acc0 += wx[j*8+hq]*x0     + wx[(j+1)*8+hq]*x1;
            acc1 += wx[j*8+hq+4]*x0   + wx[(j+1)*8+hq+4]*x1;
        }
        if(j<nc){
            float x0 = ldf(x, (long)src_l[j]*FIN + c, isf);
            acc0 += wx[j*8+hq]*x0;
            acc1 += wx[j*8+hq+4]*x0;
        }
        __syncthreads();
    }
    aggx[hq][c]   = acc0/dh[hq];
    aggx[hq+4][c] = acc1/dh[hq+4];
    __syncthreads();
    {   // z1[t] for t = h*8+cc
        int h = t>>3;
        float s = 0.f;
        #pragma unroll
        for(int k=0;k<FIN;k++) s += aggx[h][k]*w1l[k*HC1 + t];
        float zv = fmaxf(s + ldf(b1, t, isf), 0.f);
        z1[(size_t)n*HC1 + t] = zv;
        zl[t] = zv;
    }
    __syncthreads();
    if(t<8){
        float s = 0.f;
        for(int k=0;k<HC1;k++) s += zl[k]*p2s[k*8+t];
        as2[n*8+t] = s;
    } else if(t<16){
        int tt = t-8;
        float s = 0.f;
        for(int k=0;k<HC1;k++) s += zl[k]*p2d[k*8+tt];
        ad2[n*8+tt] = s;
    }
}

// ---------- layer2 aggregation in z1-space: aggz[n][h][64] ----------
__global__ __launch_bounds__(64) void k_aggz(const int* __restrict__ offs, const int* __restrict__ csr,
        const float* __restrict__ z1, const float* __restrict__ as2, const float* __restrict__ ad2,
        float* aggz){
    __shared__ float redm[64], redd[64];
    __shared__ float mh[8], dh[8], adl[8];
    __shared__ int src_l[64];
    __shared__ float wx[64*8];
    int n = blockIdx.x, t = threadIdx.x;
    int off = offs[n], deg = offs[n+1]-off, tot = deg+1;
    if(t<8) adl[t] = ad2[n*8+t];
    __syncthreads();
    {
        int h = t&7, jg = t>>3;
        float ad = adl[h];
        float m = -1e30f, d = 0.f;
        for(int j=jg; j<tot; j+=8){
            int s = (j<deg)?csr[off+j]:n;
            float e = lrelu(as2[s*8+h] + ad);
            if(e>m){ d = d*__expf(m-e) + 1.f; m = e; } else d += __expf(e-m);
        }
        redm[t]=m; redd[t]=d;
        __syncthreads();
        for(int st=4; st>=1; st>>=1){
            if(jg < st){
                float m2 = redm[t + st*8], d2 = redd[t + st*8];
                float mm = fmaxf(m, m2);
                d = d*__expf(m-mm) + d2*__expf(m2-mm);
                m = mm;
                redm[t]=m; redd[t]=d;
            }
            __syncthreads();
        }
        if(t<8){ mh[t]=redm[t]; dh[t]=redd[t] + 1e-16f; }
        __syncthreads();
    }
    float acc[8];
    #pragma unroll
    for(int h=0;h<8;h++) acc[h]=0.f;
    for(int c0=0;c0<tot;c0+=64){
        int nc = min(64, tot-c0);
        if(t<nc){ int j=c0+t; src_l[t]=(j<deg)?csr[off+j]:n; }
        __syncthreads();
        for(int p=t;p<nc*8;p+=64){
            int j=p>>3, hh=p&7;
            float e = lrelu(as2[src_l[j]*8+hh] + adl[hh]);
            wx[p] = __expf(e - mh[hh]);
        }
        __syncthreads();
        int j = 0;
        for(; j+2<=nc; j+=2){
            float z0 = z1[(size_t)src_l[j]*HC1 + t];
            float z1v = z1[(size_t)src_l[j+1]*HC1 + t];
            #pragma unroll
            for(int h=0;h<8;h++) acc[h] += wx[j*8+h]*z0 + wx[(j+1)*8+h]*z1v;
        }
        if(j<nc){
            float z0 = z1[(size_t)src_l[j]*HC1 + t];
            #pragma unroll
            for(int h=0;h<8;h++) acc[h] += wx[j*8+h]*z0;
        }
        __syncthreads();
    }
    #pragma unroll
    for(int h=0;h<8;h++)
        aggz[((size_t)n*8 + h)*HC1 + t] = acc[h]/dh[h];
}

// ---------- dense2 after aggregation: hbf[n] = relu(aggz[n] @ W2 + b2), 8 nodes/block ----------
__global__ __launch_bounds__(256) void k_d2(const float* __restrict__ aggz,
        const void* __restrict__ W2, const void* __restrict__ b2, u16* hbf, const int* flags){
    int isf = flags[0];
    __shared__ float az[8][512];     // 16 KB
    int t = threadIdx.x;
    int n0 = blockIdx.x*8;
    for(int q=0;q<16;q++){
        int f = t + q*256;
        az[f>>9][f&511] = aggz[(size_t)n0*512 + f];
    }
    __syncthreads();
    int c0 = t*4, h = t>>5;
    float acc[8][4];
    #pragma unroll
    for(int i=0;i<8;i++){ acc[i][0]=0;acc[i][1]=0;acc[i][2]=0;acc[i][3]=0; }
    for(int k=0;k<HC1;k++){
        float w0,w1,w2,w3;
        if(isf){
            float4 w = *(const float4*)((const float*)W2 + (size_t)k*HC2 + c0);
            w0=w.x; w1=w.y; w2=w.z; w3=w.w;
        } else {
            ushort4 w = *(const ushort4*)((const u16*)W2 + (size_t)k*HC2 + c0);
            w0=b2f(w.x); w1=b2f(w.y); w2=b2f(w.z); w3=b2f(w.w);
        }
        #pragma unroll
        for(int i=0;i<8;i++){
            float zv = az[i][h*64 + k];
            acc[i][0]+=zv*w0; acc[i][1]+=zv*w1; acc[i][2]+=zv*w2; acc[i][3]+=zv*w3;
        }
    }
    float bb0 = ldf(b2,c0+0,isf), bb1 = ldf(b2,c0+1,isf), bb2 = ldf(b2,c0+2,isf), bb3 = ldf(b2,c0+3,isf);
    #pragma unroll
    for(int i=0;i<8;i++){
        ushort4 o;
        o.x=f2b(fmaxf(acc[i][0]+bb0, 0.f));
        o.y=f2b(fmaxf(acc[i][1]+bb1, 0.f));
        o.z=f2b(fmaxf(acc[i][2]+bb2, 0.f));
        o.w=f2b(fmaxf(acc[i][3]+bb3, 0.f));
        *(ushort4*)&hbf[(size_t)(n0+i)*HC2 + c0] = o;
    }
}

// ---------- fused head GEMVs ----------
template<int COLS, int NW>
__device__ __forceinline__ void gemv_part(const void* __restrict__ W, const u16* __restrict__ hbf,
        float* __restrict__ scratch, int wid, int lane, int isf){
    const int GR    = COLS/8;
    const int KSTEP = 64/GR;
    const int ITERS = DTOT/(NW*KSTEP);
    int cg  = (lane % GR)*8;
    int kof = lane / GR;
    float acc[8][8];
    #pragma unroll
    for(int b=0;b<8;b++)
        #pragma unroll
        for(int c=0;c<8;c++) acc[b][c]=0.f;
    for(int it=0; it<ITERS; it+=2){
        int k0 = (it*NW + wid)*KSTEP + kof;
        int k1 = ((it+1)*NW + wid)*KSTEP + kof;
        float wv0[8], wv1[8];
        if(isf){
            float4 a0 = *(const float4*)((const float*)W + (size_t)k0*COLS + cg);
            float4 b0 = *(const float4*)((const float*)W + (size_t)k0*COLS + cg + 4);
            float4 a1 = *(const float4*)((const float*)W + (size_t)k1*COLS + cg);
            float4 b1 = *(const float4*)((const float*)W + (size_t)k1*COLS + cg + 4);
            wv0[0]=a0.x;wv0[1]=a0.y;wv0[2]=a0.z;wv0[3]=a0.w;wv0[4]=b0.x;wv0[5]=b0.y;wv0[6]=b0.z;wv0[7]=b0.w;
            wv1[0]=a1.x;wv1[1]=a1.y;wv1[2]=a1.z;wv1[3]=a1.w;wv1[4]=b1.x;wv1[5]=b1.y;wv1[6]=b1.z;wv1[7]=b1.w;
        } else {
            ushort4 a0 = *(const ushort4*)((const u16*)W + (size_t)k0*COLS + cg);
            ushort4 b0 = *(const ushort4*)((const u16*)W + (size_t)k0*COLS + cg + 4);
            ushort4 a1 = *(const ushort4*)((const u16*)W + (size_t)k1*COLS + cg);
            ushort4 b1 = *(const ushort4*)((const u16*)W + (size_t)k1*COLS + cg + 4);
            wv0[0]=b2f(a0.x);wv0[1]=b2f(a0.y);wv0[2]=b2f(a0.z);wv0[3]=b2f(a0.w);
            wv0[4]=b2f(b0.x);wv0[5]=b2f(b0.y);wv0[6]=b2f(b0.z);wv0[7]=b2f(b0.w);
            wv1[0]=b2f(a1.x);wv1[1]=b2f(a1.y);wv1[2]=b2f(a1.z);wv1[3]=b2f(a1.w);
            wv1[4]=b2f(b1.x);wv1[5]=b2f(b1.y);wv1[6]=b2f(b1.z);wv1[7]=b2f(b1.w);
        }
        float hv0[8], hv1[8];
        #pragma unroll
        for(int b=0;b<8;b++){ hv0[b] = b2f(hbf[(size_t)b*DTOT + k0]); hv1[b] = b2f(hbf[(size_t)b*DTOT + k1]); }
        #pragma unroll
        for(int b=0;b<8;b++)
            #pragma unroll
            for(int c=0;c<8;c++) acc[b][c] += hv0[b]*wv0[c] + hv1[b]*wv1[c];
    }
    #pragma unroll
    for(int m=GR;m<64;m<<=1){
        #pragma unroll
        for(int b=0;b<8;b++)
            #pragma unroll
            for(int c=0;c<8;c++) acc[b][c] += __shfl_xor(acc[b][c], m);
    }
    int q = lane / GR;
    if(q < 8){
        float4 o0, o1;
        o0.x=acc[q][0]; o0.y=acc[q][1]; o0.z=acc[q][2]; o0.w=acc[q][3];
        o1.x=acc[q][4]; o1.y=acc[q][5]; o1.z=acc[q][6]; o1.w=acc[q][7];
        float* dst = scratch + (size_t)wid*COLS*8 + q*COLS + cg;
        *(float4*)dst       = o0;
        *(float4*)(dst + 4) = o1;
    }
}

__global__ __launch_bounds__(256) void k_heads(const void* __restrict__ v1w, const void* __restrict__ advw,
        const u16* __restrict__ hbf, float* s1, float* s2, const int* flags){
    int isf = flags[0];
    int lane = threadIdx.x & 63;
    if(blockIdx.x < 1024){
        int wid = (int)((blockIdx.x*256 + threadIdx.x) >> 6);
        gemv_part<64,4096>(v1w, hbf, s1, wid, lane, isf);
    } else {
        int wid = (int)(((blockIdx.x-1024)*256 + threadIdx.x) >> 6);
        gemv_part<16,1024>(advw, hbf, s2, wid, lane, isf);
    }
}

// ---------- reduce partials ----------
__global__ __launch_bounds__(1024) void k_reduce(const float* __restrict__ s1, const float* __restrict__ s2,
        float* v1a, float* adva){
    __shared__ float red[1024];
    int blk = blockIdx.x, t = threadIdx.x;
    int ph = t>>6, ln = t&63;
    float a = 0.f;
    if(blk < 8){
        int o = blk*64 + ln;
        for(int p = ph; p < 4096; p += 16) a += s1[(size_t)p*512 + o];
        red[t] = a; __syncthreads();
        if(t<64){ float s=0.f; for(int q=0;q<16;q++) s += red[q*64+t]; v1a[blk*64+t]=s; }
    } else {
        int o = (blk-8)*64 + ln;
        for(int p = ph; p < 1024; p += 16) a += s2[(size_t)p*128 + o];
        red[t] = a; __syncthreads();
        if(t<64){ float s=0.f; for(int q=0;q<16;q++) s += red[q*64+t]; adva[(blk-8)*64+t]=s; }
    }
}

// ---------- value MLP + dueling combine ----------
__global__ __launch_bounds__(512) void k_final(const float* __restrict__ v1a, const float* __restrict__ adva,
        const void* __restrict__ v1b, const void* __restrict__ advb,
        const void* __restrict__ w2v, const void* __restrict__ b2v,
        const void* __restrict__ w3v, const void* __restrict__ b3v,
        void* out, const int* flags){
    int isf = flags[0];
    __shared__ float v1[8][64], v2[8][64], adv[128], v3[8];
    int t = threadIdx.x;
    { int b=t>>6, j=t&63; v1[b][j] = fmaxf(v1a[t] + ldf(v1b,j,isf), 0.f); }
    if(t<128) adv[t] = fmaxf(adva[t] + ldf(advb,t&15,isf), 0.f);
    __syncthreads();
    { int b=t>>6, j=t&63;
      float a=0.f;
      for(int k=0;k<64;k++) a += v1[b][k]*ldf(w2v,k*64+j,isf);
      v2[b][j] = fmaxf(a + ldf(b2v,j,isf), 0.f); }
    __syncthreads();
    if(t<8){
        float a=0.f;
        for(int k=0;k<64;k++) a += v2[t][k]*ldf(w3v,k,isf);
        v3[t] = a + ldf(b3v,0,isf);
    }
    __syncthreads();
    if(t<128){
        int b=t>>4, r=(t>>2)&3;
        int base = b*16 + r*4;
        float m = 0.25f*(adv[base]+adv[base+1]+adv[base+2]+adv[base+3]);
        float val = v3[b] + adv[t] - m;
        if(isf) ((float*)out)[t] = val;
        else    ((u16*)out)[t]   = f2b(val);
    }
}

// ---------- host ----------
extern "C" void kernel_launch(void* const* d_in, const int* in_sizes, int n_in,
                              void* d_out, int out_size, void* d_ws, size_t ws_size,
                              hipStream_t stream){
    const void* x    = d_in[0];
    const int*  edge = (const int*)d_in[1];
    const int E = in_sizes[1]/2;
    const void* W1   = d_in[2];
    const void* as1w = d_in[3];
    const void* ad1w = d_in[4];
    const void* b1   = d_in[5];
    const void* W2   = d_in[6];
    const void* as2w = d_in[7];
    const void* ad2w = d_in[8];
    const void* b2   = d_in[9];
    const void* advw = d_in[10];
    const void* advb = d_in[11];
    const void* v1w  = d_in[12];
    const void* v1b  = d_in[13];
    const void* v2w  = d_in[14];
    const void* v2b  = d_in[15];
    const void* v3w  = d_in[16];
    const void* v3b  = d_in[17];

    char* wsp = (char*)d_ws;
    size_t o = 0;
    auto alloc = [&](size_t bytes)->char*{
        char* p = wsp + o;
        o = (o + bytes + 255) & ~(size_t)255;
        return p;
    };
    int*   flags  = (int*)  alloc(256);
    int*   counts = (int*)  alloc(NODES*4);
    int*   offs   = (int*)  alloc((NODES+8)*4);
    int*   cursor = (int*)  alloc(NODES*4);
    int*   csr    = (int*)  alloc((size_t)E*4);
    float* as1    = (float*)alloc((size_t)NODES*8*4);
    float* ad1    = (float*)alloc((size_t)NODES*8*4);
    float* z1     = (float*)alloc((size_t)NODES*HC1*4);
    float* as2    = (float*)alloc((size_t)NODES*8*4);
    float* ad2    = (float*)alloc((size_t)NODES*8*4);
    float* p2s    = (float*)alloc(HC1*8*4);
    float* p2d    = (float*)alloc(HC1*8*4);
    float* aggz   = (float*)alloc((size_t)NODES*8*HC1*4);   // 16.8 MB
    u16*   hbf    = (u16*)  alloc((size_t)NODES*HC2*2);
    float* s1     = (float*)alloc((size_t)4096*512*4);
    float* s2     = (float*)alloc((size_t)1024*128*4);
    float* v1a    = (float*)alloc(512*4);
    float* adva   = (float*)alloc(128*4);

    k_prep   <<<33, 256, 0, stream>>>((const u16*)x, edge, flags, counts);
    k_cnt_a1 <<<576, 256, 0, stream>>>(edge, E, counts, x, W1, as1w, ad1w, as1, ad1, flags);
    k_scan   <<<1, 1024, 0, stream>>>(counts, offs, cursor);
    k_fill_p2<<<513, 256, 0, stream>>>(edge, E, cursor, csr, W2, as2w, ad2w, p2s, p2d, flags);
    k_l1     <<<NODES, 64, 0, stream>>>(offs, csr, x, W1, b1, as1, ad1, p2s, p2d, z1, as2, ad2, flags);
    k_aggz   <<<NODES, 64, 0, stream>>>(offs, csr, z1, as2, ad2, aggz);
    k_d2     <<<NODES/8, 256, 0, stream>>>(aggz, W2, b2, hbf, flags);
    k_heads  <<<1280, 256, 0, stream>>>(v1w, advw, hbf, s1, s2, flags);
    k_reduce <<<10, 1024, 0, stream>>>(s1, s2, v1a, adva);
    k_final  <<<1, 512, 0, stream>>>(v1a, adva, v1b, advb, v2w, v2b, v3w, v3b, d_out, flags);
}